// Round 2
// baseline (700.663 us; speedup 1.0000x reference)
//
#include <hip/hip_runtime.h>
#include <math.h>

#define T_TOTAL 16384   // B*S
#define C_DIM   4096
#define E_DIM   64
#define K_TOP   8
#define S_SEQ   4096
#define B_BATCH 4
#define TOK_PER_BLK   64   // lane = token in phase 1
#define EXP_PER_WAVE  16   // wave = 16 experts in phase 1

// ---- fused gate kernel ----
// Phase 1: logits GEMV. lane = token (coalesced-ish per-lane row streams),
//          wave wv handles experts [wv*16, wv*16+16). Chunked f32 accumulation
//          (flush every 256 elements) for ~1e-5 logit accuracy.
// Phase 2: transpose via LDS; lane = expert; shfl-butterfly top-8.
__global__ __launch_bounds__(256, 1)
void gate_kernel(const float* __restrict__ x,
                 const float* __restrict__ w,
                 const float* __restrict__ expert_bias,
                 float* __restrict__ out,
                 float* __restrict__ facc,
                 float* __restrict__ pacc) {
    const int lane = threadIdx.x & 63;
    const int wv   = threadIdx.x >> 6;
    const int blk  = blockIdx.x;
    const int tok  = blk * TOK_PER_BLK + lane;   // this lane's token
    const int e0   = wv * EXP_PER_WAVE;          // this wave's first expert

    const float4* xr = reinterpret_cast<const float4*>(x + (size_t)tok * C_DIM);
    const float4* wr[EXP_PER_WAVE];
#pragma unroll
    for (int j = 0; j < EXP_PER_WAVE; ++j)
        wr[j] = reinterpret_cast<const float4*>(w + (size_t)(e0 + j) * C_DIM);

    float acc[EXP_PER_WAVE];
#pragma unroll
    for (int j = 0; j < EXP_PER_WAVE; ++j) acc[j] = 0.0f;

    // 16 outer chunks x 64 float4 (256 elements) per chunk
    for (int cc = 0; cc < 16; ++cc) {
        float inner[EXP_PER_WAVE];
#pragma unroll
        for (int j = 0; j < EXP_PER_WAVE; ++j) inner[j] = 0.0f;
#pragma unroll 2
        for (int i = 0; i < 64; ++i) {
            const int c4 = cc * 64 + i;
            const float4 xv = xr[c4];            // per-lane row stream
#pragma unroll
            for (int j = 0; j < EXP_PER_WAVE; ++j) {
                const float4 wv4 = wr[j][c4];    // wave-uniform broadcast (L2)
                float t = inner[j];
                t = fmaf(xv.x, wv4.x, t);
                t = fmaf(xv.y, wv4.y, t);
                t = fmaf(xv.z, wv4.z, t);
                t = fmaf(xv.w, wv4.w, t);
                inner[j] = t;
            }
        }
#pragma unroll
        for (int j = 0; j < EXP_PER_WAVE; ++j) acc[j] += inner[j];
    }

    // transpose logits through LDS: stride 65 -> conflict-free
    __shared__ float slog[TOK_PER_BLK * 65];
#pragma unroll
    for (int j = 0; j < EXP_PER_WAVE; ++j)
        slog[lane * 65 + e0 + j] = acc[j];
    __syncthreads();

    // ---- phase 2: lane = expert; wave wv handles tokens [wv*16, wv*16+16)
    const float be = expert_bias[lane];
    const int   b  = (blk * TOK_PER_BLK) / S_SEQ;   // uniform per block
    float f_local = 0.0f, p_local = 0.0f;

    for (int m = 0; m < 16; ++m) {
        const int t = blk * TOK_PER_BLK + wv * 16 + m;
        const float logit = slog[(wv * 16 + m) * 65 + lane];
        const float sc = 1.0f / (1.0f + expf(-logit));   // sigmoid
        float ssum = sc;
#pragma unroll
        for (int off = 32; off >= 1; off >>= 1) ssum += __shfl_xor(ssum, off, 64);
        p_local += sc / (ssum + 1e-10f);

        // top-8 over biased logits (descending, lowest-index tie-break)
        float v = logit + be;
        float wsum = 0.0f, my_w = 0.0f;
        int   my_i = 0;
#pragma unroll
        for (int k = 0; k < K_TOP; ++k) {
            float rv = v;
            int   ri = lane;
#pragma unroll
            for (int off = 32; off >= 1; off >>= 1) {
                float ov = __shfl_xor(rv, off, 64);
                int   oi = __shfl_xor(ri, off, 64);
                if (ov > rv || (ov == rv && oi < ri)) { rv = ov; ri = oi; }
            }
            float wsc = __shfl(sc, ri, 64);   // winner's score (uniform)
            wsum += wsc;
            if (lane == k)  { my_i = ri; my_w = wsc; }
            if (lane == ri) { v = -INFINITY; f_local += 1.0f; }
        }
        if (lane < K_TOP) {
            out[(size_t)t * K_TOP + lane] = (float)my_i;
            out[(size_t)T_TOTAL * K_TOP + (size_t)t * K_TOP + lane] =
                my_w / (wsum + 1e-10f);
        }
    }

    atomicAdd(&facc[b * E_DIM + lane], f_local);
    atomicAdd(&pacc[b * E_DIM + lane], p_local);
}

// ---- tiny loss reduction: 4x64 f*p -> scalar ----
__global__ void loss_kernel(const float* __restrict__ facc,
                            const float* __restrict__ pacc,
                            float* __restrict__ out_loss) {
    const int tid = threadIdx.x;                 // 256 threads = B*E
    float f = facc[tid] * (1.0f / ((float)K_TOP * (float)S_SEQ));
    float p = pacc[tid] * (1.0f / (float)S_SEQ);
    float v = f * p;
#pragma unroll
    for (int off = 32; off >= 1; off >>= 1) v += __shfl_xor(v, off, 64);
    __shared__ float s[4];
    if ((tid & 63) == 0) s[tid >> 6] = v;
    __syncthreads();
    if (tid == 0) {
        float tot = s[0] + s[1] + s[2] + s[3];
        out_loss[0] = 0.001f * tot / (float)B_BATCH;
    }
}

extern "C" void kernel_launch(void* const* d_in, const int* in_sizes, int n_in,
                              void* d_out, int out_size, void* d_ws, size_t ws_size,
                              hipStream_t stream) {
    const float* x    = (const float*)d_in[0];   // [4,4096,4096] f32
    const float* w    = (const float*)d_in[1];   // [64,4096] f32
    const float* bias = (const float*)d_in[2];   // [64] f32
    float* out = (float*)d_out;                  // [131072 idx][131072 w][1 loss]

    float* facc = (float*)d_ws;                  // 256 floats
    float* pacc = facc + B_BATCH * E_DIM;        // 256 floats

    // zero the f/p accumulators every call (atomics accumulate)
    hipMemsetAsync(d_ws, 0, 2048, stream);

    gate_kernel<<<T_TOTAL / TOK_PER_BLK, 256, 0, stream>>>(
        x, w, bias, out, facc, pacc);

    loss_kernel<<<1, 256, 0, stream>>>(facc, pacc, out + 2 * (size_t)T_TOTAL * K_TOP);
}

// Round 3
// 662.084 us; speedup vs baseline: 1.0583x; 1.0583x over previous
//
#include <hip/hip_runtime.h>
#include <math.h>

#define T_TOTAL 16384   // B*S
#define C_DIM   4096
#define E_DIM   64
#define K_TOP   8
#define S_SEQ   4096
#define B_BATCH 4

#define TOK_PER_BLK 16
#define CH_LEN      2048   // C elements per wave (half of C)
#define EH_LEN      32     // experts per wave (half of E)

// Block = 16 tokens. 4 waves partition (C-half x expert-half):
//   wave wv: ch = wv>>1 (C half), eh = wv&1 (expert half)
//   lane: t = lane>>2 (token 0..15), s = lane&3 (c sub-slot)
// Phase 1: GEMV partials. Phase 2 (after LDS meet): lane = expert, top-8.
__global__ __launch_bounds__(256, 4)
void gate_kernel(const float* __restrict__ x,
                 const float* __restrict__ w,
                 const float* __restrict__ expert_bias,
                 float* __restrict__ out,
                 float* __restrict__ facc,
                 float* __restrict__ pacc) {
    const int lane = threadIdx.x & 63;
    const int wv   = threadIdx.x >> 6;
    const int ch   = wv >> 1;
    const int eh   = wv & 1;
    const int t    = lane >> 2;
    const int s    = lane & 3;
    const int tok0 = blockIdx.x * TOK_PER_BLK;

    // lane's float4 stream: token (tok0+t), C offset ch*2048 + k*16 + s*4
    const float4* xr = reinterpret_cast<const float4*>(
        x + (size_t)(tok0 + t) * C_DIM + (size_t)ch * CH_LEN) + s;
    const float4* wr = reinterpret_cast<const float4*>(
        w + (size_t)(eh * EH_LEN) * C_DIM + (size_t)ch * CH_LEN) + s;
    // expert e's float4 at k-step k: wr[e*1024 + k*4]

    float acc[EH_LEN];
#pragma unroll
    for (int e = 0; e < EH_LEN; ++e) acc[e] = 0.0f;

    // 2 chunks x 64 k-steps; per k-step each lane eats one float4 (16 floats/wave-row)
    for (int cc = 0; cc < 2; ++cc) {
        float inner[EH_LEN];
#pragma unroll
        for (int e = 0; e < EH_LEN; ++e) inner[e] = 0.0f;
#pragma unroll 2
        for (int k = 0; k < 64; ++k) {
            const int o = (cc * 64 + k) * 4;
            const float4 xv = xr[o];
#pragma unroll
            for (int eg = 0; eg < EH_LEN / 4; ++eg) {
                const float4 w0 = wr[(size_t)(eg * 4 + 0) * 1024 + o];
                const float4 w1 = wr[(size_t)(eg * 4 + 1) * 1024 + o];
                const float4 w2 = wr[(size_t)(eg * 4 + 2) * 1024 + o];
                const float4 w3 = wr[(size_t)(eg * 4 + 3) * 1024 + o];
                float a0 = inner[eg * 4 + 0], a1 = inner[eg * 4 + 1];
                float a2 = inner[eg * 4 + 2], a3 = inner[eg * 4 + 3];
                a0 = fmaf(xv.x, w0.x, a0); a0 = fmaf(xv.y, w0.y, a0);
                a0 = fmaf(xv.z, w0.z, a0); a0 = fmaf(xv.w, w0.w, a0);
                a1 = fmaf(xv.x, w1.x, a1); a1 = fmaf(xv.y, w1.y, a1);
                a1 = fmaf(xv.z, w1.z, a1); a1 = fmaf(xv.w, w1.w, a1);
                a2 = fmaf(xv.x, w2.x, a2); a2 = fmaf(xv.y, w2.y, a2);
                a2 = fmaf(xv.z, w2.z, a2); a2 = fmaf(xv.w, w2.w, a2);
                a3 = fmaf(xv.x, w3.x, a3); a3 = fmaf(xv.y, w3.y, a3);
                a3 = fmaf(xv.z, w3.z, a3); a3 = fmaf(xv.w, w3.w, a3);
                inner[eg * 4 + 0] = a0; inner[eg * 4 + 1] = a1;
                inner[eg * 4 + 2] = a2; inner[eg * 4 + 3] = a3;
            }
        }
#pragma unroll
        for (int e = 0; e < EH_LEN; ++e) acc[e] += inner[e];
    }

    // reduce over the 4 c-slots (deterministic butterfly)
#pragma unroll
    for (int e = 0; e < EH_LEN; ++e) {
        acc[e] += __shfl_xor(acc[e], 1, 64);
        acc[e] += __shfl_xor(acc[e], 2, 64);
    }

    // meet in LDS: slog[ch][token][expert], stride 65 -> conflict-free
    __shared__ float slog[2][TOK_PER_BLK][65];
    if (s == 0) {
#pragma unroll
        for (int e = 0; e < EH_LEN; ++e)
            slog[ch][t][eh * EH_LEN + e] = acc[e];
    }
    __syncthreads();

    // ---- phase 2: lane = expert; wave wv handles tokens wv*4 .. wv*4+3
    const float be = expert_bias[lane];
    const int   b  = tok0 / S_SEQ;               // uniform per block
    float f_local = 0.0f, p_local = 0.0f;

    for (int m = 0; m < 4; ++m) {
        const int tl = wv * 4 + m;
        const int tk = tok0 + tl;
        const float logit = slog[0][tl][lane] + slog[1][tl][lane];
        const float sc = 1.0f / (1.0f + expf(-logit));   // sigmoid
        float ssum = sc;
#pragma unroll
        for (int off = 32; off >= 1; off >>= 1) ssum += __shfl_xor(ssum, off, 64);
        p_local += sc / (ssum + 1e-10f);

        // top-8 over biased logits (descending, lowest-index tie-break)
        float v = logit + be;
        float wsum = 0.0f, my_w = 0.0f;
        int   my_i = 0;
#pragma unroll
        for (int k = 0; k < K_TOP; ++k) {
            float rv = v;
            int   ri = lane;
#pragma unroll
            for (int off = 32; off >= 1; off >>= 1) {
                float ov = __shfl_xor(rv, off, 64);
                int   oi = __shfl_xor(ri, off, 64);
                if (ov > rv || (ov == rv && oi < ri)) { rv = ov; ri = oi; }
            }
            float wsc = __shfl(sc, ri, 64);   // winner's score (uniform)
            wsum += wsc;
            if (lane == k)  { my_i = ri; my_w = wsc; }
            if (lane == ri) { v = -INFINITY; f_local += 1.0f; }
        }
        if (lane < K_TOP) {
            out[(size_t)tk * K_TOP + lane] = (float)my_i;
            out[(size_t)T_TOTAL * K_TOP + (size_t)tk * K_TOP + lane] =
                my_w / (wsum + 1e-10f);
        }
    }

    atomicAdd(&facc[b * E_DIM + lane], f_local);
    atomicAdd(&pacc[b * E_DIM + lane], p_local);
}

// ---- tiny loss reduction: 4x64 f*p -> scalar ----
__global__ void loss_kernel(const float* __restrict__ facc,
                            const float* __restrict__ pacc,
                            float* __restrict__ out_loss) {
    const int tid = threadIdx.x;                 // 256 threads = B*E
    float f = facc[tid] * (1.0f / ((float)K_TOP * (float)S_SEQ));
    float p = pacc[tid] * (1.0f / (float)S_SEQ);
    float v = f * p;
#pragma unroll
    for (int off = 32; off >= 1; off >>= 1) v += __shfl_xor(v, off, 64);
    __shared__ float sred[4];
    if ((tid & 63) == 0) sred[tid >> 6] = v;
    __syncthreads();
    if (tid == 0) {
        float tot = sred[0] + sred[1] + sred[2] + sred[3];
        out_loss[0] = 0.001f * tot / (float)B_BATCH;
    }
}

extern "C" void kernel_launch(void* const* d_in, const int* in_sizes, int n_in,
                              void* d_out, int out_size, void* d_ws, size_t ws_size,
                              hipStream_t stream) {
    const float* x    = (const float*)d_in[0];   // [4,4096,4096] f32
    const float* w    = (const float*)d_in[1];   // [64,4096] f32
    const float* bias = (const float*)d_in[2];   // [64] f32
    float* out = (float*)d_out;                  // [131072 idx][131072 w][1 loss]

    float* facc = (float*)d_ws;                  // 256 floats
    float* pacc = facc + B_BATCH * E_DIM;        // 256 floats

    // zero the f/p accumulators every call (atomics accumulate)
    hipMemsetAsync(d_ws, 0, 2048, stream);

    gate_kernel<<<T_TOTAL / TOK_PER_BLK, 256, 0, stream>>>(
        x, w, bias, out, facc, pacc);

    loss_kernel<<<1, 256, 0, stream>>>(facc, pacc, out + 2 * (size_t)T_TOTAL * K_TOP);
}

// Round 4
// 559.871 us; speedup vs baseline: 1.2515x; 1.1826x over previous
//
#include <hip/hip_runtime.h>
#include <math.h>

#define T_TOTAL 16384   // B*S
#define C_DIM   4096
#define E_DIM   64
#define K_TOP   8
#define S_SEQ   4096
#define B_BATCH 4

#define TOK_PER_BLK 16
#define E_PER_WAVE  16   // each wave: 16 experts x full C

// Block = 16 tokens, 4 waves. Wave wv owns experts [wv*16, wv*16+16) over ALL
// of C (no cross-wave partials). Lane = (t = lane>>2: token, s = lane&3:
// c-slot). Proven numerics: 256-element inner chunks -> acc, butterfly over
// the 4 c-slots. Phase 2 (lane = expert) identical to the verified epilogue.
__global__ __launch_bounds__(256, 4)
void gate_kernel(const float* __restrict__ x,
                 const float* __restrict__ w,
                 const float* __restrict__ expert_bias,
                 float* __restrict__ out,
                 float* __restrict__ facc,
                 float* __restrict__ pacc) {
    const int lane = threadIdx.x & 63;
    const int wv   = threadIdx.x >> 6;
    const int t    = lane >> 2;
    const int s    = lane & 3;
    const int tok0 = blockIdx.x * TOK_PER_BLK;
    const int e0   = wv * E_PER_WAVE;

    // lane's x stream: token tok0+t, float4 index k*4 + s  (64B/lane-step)
    const float4* xr = reinterpret_cast<const float4*>(
        x + (size_t)(tok0 + t) * C_DIM) + s;
    const float4* wr = reinterpret_cast<const float4*>(
        w + (size_t)e0 * C_DIM) + s;
    // expert e0+j at k-step k: wr[j*1024 + k*4]

    float acc[E_PER_WAVE];
#pragma unroll
    for (int j = 0; j < E_PER_WAVE; ++j) acc[j] = 0.0f;

    // 4 chunks x 64 k-steps (256 elements per inner chain -> proven accuracy)
    for (int cc = 0; cc < 4; ++cc) {
        float inner[E_PER_WAVE];
#pragma unroll
        for (int j = 0; j < E_PER_WAVE; ++j) inner[j] = 0.0f;
#pragma unroll 8
        for (int k = 0; k < 64; ++k) {
            const int o = (cc * 64 + k) * 4;
            const float4 xv = xr[o];
#pragma unroll
            for (int j = 0; j < E_PER_WAVE; ++j) {
                const float4 wj = wr[(size_t)j * 1024 + o];
                float a = inner[j];
                a = fmaf(xv.x, wj.x, a);
                a = fmaf(xv.y, wj.y, a);
                a = fmaf(xv.z, wj.z, a);
                a = fmaf(xv.w, wj.w, a);
                inner[j] = a;
            }
        }
#pragma unroll
        for (int j = 0; j < E_PER_WAVE; ++j) acc[j] += inner[j];
    }

    // reduce the 4 c-slots (deterministic butterfly); lanes s==0 hold totals
#pragma unroll
    for (int j = 0; j < E_PER_WAVE; ++j) {
        acc[j] += __shfl_xor(acc[j], 1, 64);
        acc[j] += __shfl_xor(acc[j], 2, 64);
    }

    // meet in LDS: slog[token][expert], stride 65 -> conflict-free
    __shared__ float slog[TOK_PER_BLK][65];
    if (s == 0) {
#pragma unroll
        for (int j = 0; j < E_PER_WAVE; ++j)
            slog[t][e0 + j] = acc[j];
    }
    __syncthreads();

    // ---- phase 2: lane = expert; wave wv handles tokens wv*4 .. wv*4+3
    const float be = expert_bias[lane];
    const int   b  = tok0 / S_SEQ;               // uniform per block
    float f_local = 0.0f, p_local = 0.0f;

    for (int m = 0; m < 4; ++m) {
        const int tl = wv * 4 + m;
        const int tk = tok0 + tl;
        const float logit = slog[tl][lane];
        const float sc = 1.0f / (1.0f + expf(-logit));   // sigmoid
        float ssum = sc;
#pragma unroll
        for (int off = 32; off >= 1; off >>= 1) ssum += __shfl_xor(ssum, off, 64);
        p_local += sc / (ssum + 1e-10f);

        // top-8 over biased logits (descending, lowest-index tie-break)
        float v = logit + be;
        float wsum = 0.0f, my_w = 0.0f;
        int   my_i = 0;
#pragma unroll
        for (int k = 0; k < K_TOP; ++k) {
            float rv = v;
            int   ri = lane;
#pragma unroll
            for (int off = 32; off >= 1; off >>= 1) {
                float ov = __shfl_xor(rv, off, 64);
                int   oi = __shfl_xor(ri, off, 64);
                if (ov > rv || (ov == rv && oi < ri)) { rv = ov; ri = oi; }
            }
            float wsc = __shfl(sc, ri, 64);   // winner's score (uniform)
            wsum += wsc;
            if (lane == k)  { my_i = ri; my_w = wsc; }
            if (lane == ri) { v = -INFINITY; f_local += 1.0f; }
        }
        if (lane < K_TOP) {
            out[(size_t)tk * K_TOP + lane] = (float)my_i;
            out[(size_t)T_TOTAL * K_TOP + (size_t)tk * K_TOP + lane] =
                my_w / (wsum + 1e-10f);
        }
    }

    atomicAdd(&facc[b * E_DIM + lane], f_local);
    atomicAdd(&pacc[b * E_DIM + lane], p_local);
}

// ---- tiny loss reduction: 4x64 f*p -> scalar ----
__global__ void loss_kernel(const float* __restrict__ facc,
                            const float* __restrict__ pacc,
                            float* __restrict__ out_loss) {
    const int tid = threadIdx.x;                 // 256 threads = B*E
    float f = facc[tid] * (1.0f / ((float)K_TOP * (float)S_SEQ));
    float p = pacc[tid] * (1.0f / (float)S_SEQ);
    float v = f * p;
#pragma unroll
    for (int off = 32; off >= 1; off >>= 1) v += __shfl_xor(v, off, 64);
    __shared__ float sred[4];
    if ((tid & 63) == 0) sred[tid >> 6] = v;
    __syncthreads();
    if (tid == 0) {
        float tot = sred[0] + sred[1] + sred[2] + sred[3];
        out_loss[0] = 0.001f * tot / (float)B_BATCH;
    }
}

extern "C" void kernel_launch(void* const* d_in, const int* in_sizes, int n_in,
                              void* d_out, int out_size, void* d_ws, size_t ws_size,
                              hipStream_t stream) {
    const float* x    = (const float*)d_in[0];   // [4,4096,4096] f32
    const float* w    = (const float*)d_in[1];   // [64,4096] f32
    const float* bias = (const float*)d_in[2];   // [64] f32
    float* out = (float*)d_out;                  // [131072 idx][131072 w][1 loss]

    float* facc = (float*)d_ws;                  // 256 floats
    float* pacc = facc + B_BATCH * E_DIM;        // 256 floats

    // zero the f/p accumulators every call (atomics accumulate)
    hipMemsetAsync(d_ws, 0, 2048, stream);

    gate_kernel<<<T_TOTAL / TOK_PER_BLK, 256, 0, stream>>>(
        x, w, bias, out, facc, pacc);

    loss_kernel<<<1, 256, 0, stream>>>(facc, pacc, out + 2 * (size_t)T_TOTAL * K_TOP);
}

// Round 5
// 486.251 us; speedup vs baseline: 1.4409x; 1.1514x over previous
//
#include <hip/hip_runtime.h>
#include <math.h>

#define T_TOTAL 16384   // B*S
#define C_DIM   4096
#define E_DIM   64
#define K_TOP   8
#define S_SEQ   4096
#define B_BATCH 4
#define KQ_LEN  1024    // channels per K-quarter

// ---- kernel 1: partial GEMV, K split 4-ways across blocks ----
// grid = 1024: block b = (tg = b&255 token-group of 64, kq = b>>8 K-quarter).
// 4 waves; wave wv owns experts [16wv,16wv+16); lane = token.
// W addresses made wave-uniform via readfirstlane -> scalar-pipe s_loads
// (w floats become SGPR operands of v_fma_f32); x is 1 coalesced b128/lane.
// Numerics: serial in-channel-order chains flushed every 256 elements
// (identical grouping to the verified r2-r4 kernels).
__global__ __launch_bounds__(256, 4)
void gemv_part_kernel(const float* __restrict__ x,
                      const float* __restrict__ w,
                      float* __restrict__ part) {
    const int lane = threadIdx.x & 63;
    const int wv   = threadIdx.x >> 6;
    const int tg   = blockIdx.x & 255;
    const int kq   = blockIdx.x >> 8;
    const int tok  = tg * 64 + lane;
    const int e0   = __builtin_amdgcn_readfirstlane(wv * 16);
    const int k0   = kq * KQ_LEN;

    const float4* xr = reinterpret_cast<const float4*>(
        x + (size_t)tok * C_DIM + k0);               // per-lane row stream
    const float* wb = w + (size_t)e0 * C_DIM + k0;   // wave-uniform base

    float acc[16];
#pragma unroll
    for (int j = 0; j < 16; ++j) acc[j] = 0.0f;

    // 4 chunks x 256 channels; chunk = 16 kb-blocks of 16 channels
    for (int cc = 0; cc < 4; ++cc) {
        float inner[16];
#pragma unroll
        for (int j = 0; j < 16; ++j) inner[j] = 0.0f;
#pragma unroll 2
        for (int kb = 0; kb < 16; ++kb) {
            float4 xv[4];
#pragma unroll
            for (int i = 0; i < 4; ++i)
                xv[i] = xr[cc * 64 + kb * 4 + i];    // 16 channels of x
#pragma unroll
            for (int j = 0; j < 16; ++j) {
                const float* wj = wb + (size_t)j * C_DIM + (cc * 256 + kb * 16);
                float a = inner[j];
#pragma unroll
                for (int i = 0; i < 4; ++i) {        // uniform -> s_load_dwordx
                    a = fmaf(xv[i].x, wj[4 * i + 0], a);
                    a = fmaf(xv[i].y, wj[4 * i + 1], a);
                    a = fmaf(xv[i].z, wj[4 * i + 2], a);
                    a = fmaf(xv[i].w, wj[4 * i + 3], a);
                }
                inner[j] = a;
            }
        }
#pragma unroll
        for (int j = 0; j < 16; ++j) acc[j] += inner[j];
    }

    // store partials: part[kq][tok][64 experts]; lane's 16 experts contiguous
    float4* pp = reinterpret_cast<float4*>(
        part + ((size_t)kq * T_TOTAL + tok) * E_DIM + e0);
#pragma unroll
    for (int g = 0; g < 4; ++g)
        pp[g] = make_float4(acc[4 * g], acc[4 * g + 1],
                            acc[4 * g + 2], acc[4 * g + 3]);
}

// ---- kernel 2: reduce quarters + sigmoid + top-8 + f/p partials ----
// Block = 64 tokens, 4 waves. Phase A: lane (tt=lane>>2, s=lane&3) sums the
// 4 quarters for token wv*16+tt, experts [16s,16s+16) -> slog. Phase B:
// the verified r2 epilogue verbatim (lane = expert, 16 tokens per wave).
__global__ __launch_bounds__(256, 4)
void topk_kernel(const float* __restrict__ part,
                 const float* __restrict__ expert_bias,
                 float* __restrict__ out,
                 float* __restrict__ facc,
                 float* __restrict__ pacc) {
    const int lane = threadIdx.x & 63;
    const int wv   = threadIdx.x >> 6;
    const int tok0 = blockIdx.x * 64;

    __shared__ float slog[64][65];

    const int tt  = lane >> 2;
    const int s   = lane & 3;
    const int tl  = wv * 16 + tt;          // token-in-block
    const int tok = tok0 + tl;

    float4 sum4[4];
#pragma unroll
    for (int i = 0; i < 4; ++i) sum4[i] = make_float4(0.f, 0.f, 0.f, 0.f);
#pragma unroll
    for (int kq = 0; kq < 4; ++kq) {       // serial quarter sum (deterministic)
        const float4* pp = reinterpret_cast<const float4*>(
            part + ((size_t)kq * T_TOTAL + tok) * E_DIM + 16 * s);
#pragma unroll
        for (int i = 0; i < 4; ++i) {
            float4 v = pp[i];
            sum4[i].x += v.x; sum4[i].y += v.y;
            sum4[i].z += v.z; sum4[i].w += v.w;
        }
    }
#pragma unroll
    for (int i = 0; i < 4; ++i) {
        slog[tl][16 * s + 4 * i + 0] = sum4[i].x;
        slog[tl][16 * s + 4 * i + 1] = sum4[i].y;
        slog[tl][16 * s + 4 * i + 2] = sum4[i].z;
        slog[tl][16 * s + 4 * i + 3] = sum4[i].w;
    }
    __syncthreads();

    // ---- phase B: lane = expert; wave wv handles tokens wv*16 .. wv*16+15
    const float be = expert_bias[lane];
    const int   b  = tok0 / S_SEQ;         // uniform per block
    float f_local = 0.0f, p_local = 0.0f;

    for (int m = 0; m < 16; ++m) {
        const int tl2 = wv * 16 + m;
        const int tk  = tok0 + tl2;
        const float logit = slog[tl2][lane];
        const float sc = 1.0f / (1.0f + expf(-logit));   // sigmoid
        float ssum = sc;
#pragma unroll
        for (int off = 32; off >= 1; off >>= 1) ssum += __shfl_xor(ssum, off, 64);
        p_local += sc / (ssum + 1e-10f);

        // top-8 over biased logits (descending, lowest-index tie-break)
        float v = logit + be;
        float wsum = 0.0f, my_w = 0.0f;
        int   my_i = 0;
#pragma unroll
        for (int k = 0; k < K_TOP; ++k) {
            float rv = v;
            int   ri = lane;
#pragma unroll
            for (int off = 32; off >= 1; off >>= 1) {
                float ov = __shfl_xor(rv, off, 64);
                int   oi = __shfl_xor(ri, off, 64);
                if (ov > rv || (ov == rv && oi < ri)) { rv = ov; ri = oi; }
            }
            float wsc = __shfl(sc, ri, 64);   // winner's score (uniform)
            wsum += wsc;
            if (lane == k)  { my_i = ri; my_w = wsc; }
            if (lane == ri) { v = -INFINITY; f_local += 1.0f; }
        }
        if (lane < K_TOP) {
            out[(size_t)tk * K_TOP + lane] = (float)my_i;
            out[(size_t)T_TOTAL * K_TOP + (size_t)tk * K_TOP + lane] =
                my_w / (wsum + 1e-10f);
        }
    }

    atomicAdd(&facc[b * E_DIM + lane], f_local);
    atomicAdd(&pacc[b * E_DIM + lane], p_local);
}

// ---- tiny loss reduction: 4x64 f*p -> scalar ----
__global__ void loss_kernel(const float* __restrict__ facc,
                            const float* __restrict__ pacc,
                            float* __restrict__ out_loss) {
    const int tid = threadIdx.x;                 // 256 threads = B*E
    float f = facc[tid] * (1.0f / ((float)K_TOP * (float)S_SEQ));
    float p = pacc[tid] * (1.0f / (float)S_SEQ);
    float v = f * p;
#pragma unroll
    for (int off = 32; off >= 1; off >>= 1) v += __shfl_xor(v, off, 64);
    __shared__ float sred[4];
    if ((tid & 63) == 0) sred[tid >> 6] = v;
    __syncthreads();
    if (tid == 0) {
        float tot = sred[0] + sred[1] + sred[2] + sred[3];
        out_loss[0] = 0.001f * tot / (float)B_BATCH;
    }
}

extern "C" void kernel_launch(void* const* d_in, const int* in_sizes, int n_in,
                              void* d_out, int out_size, void* d_ws, size_t ws_size,
                              hipStream_t stream) {
    const float* x    = (const float*)d_in[0];   // [4,4096,4096] f32
    const float* w    = (const float*)d_in[1];   // [64,4096] f32
    const float* bias = (const float*)d_in[2];   // [64] f32
    float* out = (float*)d_out;                  // [131072 idx][131072 w][1 loss]

    float* facc = (float*)d_ws;                  // 256 floats
    float* pacc = facc + B_BATCH * E_DIM;        // 256 floats
    float* part = (float*)((char*)d_ws + 4096);  // 4 x 16384 x 64 f32 = 16 MB

    // zero the f/p accumulators every call (atomics accumulate)
    hipMemsetAsync(d_ws, 0, 2048, stream);

    gemv_part_kernel<<<1024, 256, 0, stream>>>(x, w, part);

    topk_kernel<<<T_TOTAL / 64, 256, 0, stream>>>(part, bias, out, facc, pacc);

    loss_kernel<<<1, 256, 0, stream>>>(facc, pacc, out + 2 * (size_t)T_TOTAL * K_TOP);
}